// Round 14
// baseline (175.499 us; speedup 1.0000x reference)
//
#include <hip/hip_runtime.h>
#include <math.h>

#define G 64
#define NDIM 512
#define FIN 7
#define HID 64
#define CLS 2
#define KPOOL 128

typedef unsigned long long u64;

__device__ __forceinline__ float wred64(float v){
  #pragma unroll
  for (int o = 32; o > 0; o >>= 1) v += __shfl_xor(v, o, 64);
  return v;
}

// XCD-aware decode for 512-block per-graph-chunk kernels
#define XCD_DECODE(bid, g, chunk) \
  const int g = ((bid) & 7) + 8 * (((bid) >> 3) & 7); \
  const int chunk = (bid) >> 6;

// ---- build transposed bitmasks: maskT[g][u][i] bit l = adj[g][i][u*64+l] ---
__global__ __launch_bounds__(256) void mask_kernel(const float* __restrict__ adj,
                                                   u64* __restrict__ maskT){
  const int wid = threadIdx.x >> 6, lane = threadIdx.x & 63;
  const int row = blockIdx.x * 4 + wid;          // [0, G*NDIM)
  const int g = row >> 9, i = row & 511;
  const float* ar = adj + (size_t)row * NDIM;
  u64 b[8];
  #pragma unroll
  for (int u = 0; u < 8; u++)
    b[u] = __ballot(ar[u * 64 + lane] != 0.0f);
  if (lane == 0){
    u64* mt = maskT + (size_t)g * 8 * NDIM + i;
    #pragma unroll
    for (int u = 0; u < 8; u++) mt[(size_t)u * NDIM] = b[u];
  }
}

// ---- mega: per-block (g, 64-row chunk): stage masks, compute deg/d2/d3/dd,
//      z, w1, w2 for ALL 512 rows locally (redundant, no grid deps);
//      w3 + h + score for OWN 64 rows. LDS = 64 KB with aliasing.
__global__ __launch_bounds__(256) void mega_kernel(
    const u64* __restrict__ maskT, const float* __restrict__ x,
    const float* __restrict__ panw, const float* __restrict__ w1,
    const float* __restrict__ b1, const float* __restrict__ pvec,
    const float* __restrict__ beta,
    float* __restrict__ dvec, float* __restrict__ score,
    float* __restrict__ hbuf)
{
  __shared__ __align__(16) char smem[65536];
  u64 (*mt)[NDIM] = (u64 (*)[NDIM])smem;            // [0, 32K) alive always
  float* deg_s = (float*)(smem + 32768);            // [32K, 34K) dies after d2-reads
  float* d2_s  = (float*)(smem + 34816);            // [34K, 36K) dies after d3 stage
  float* zA    = (float*)(smem + 32768);            // [32K, 48K) born at z stage
  float* zB    = (float*)(smem + 49152);            // [48K, 64K) born at w1 stage
  float* Wl    = (float*)(smem + 49152);            // reuse zB after w2 for weights

  const int bid = blockIdx.x;
  XCD_DECODE(bid, g, chunk)
  const int tid = threadIdx.x;
  {
    const uint4* s4 = (const uint4*)(maskT + (size_t)g * 8 * NDIM);
    uint4* d4 = (uint4*)smem;
    #pragma unroll
    for (int s = 0; s < 8; s++) d4[tid + 256 * s] = s4[tid + 256 * s];
  }
  __syncthreads();
  const float w0 = panw[0], ww1 = panw[1], ww2 = panw[2], ww3 = panw[3];
  const float c0 = w0, c1 = c0 * ww1, c2 = c1 * ww2, c3 = c2 * ww3;
  const int r0 = tid, r1 = tid + 256;
  const bool own0 = (r0 >> 6) == chunk, own1 = (r1 >> 6) == chunk;

  // deg for all rows
  float dg0 = 0.f, dg1 = 0.f;
  #pragma unroll
  for (int u = 0; u < 8; u++){
    dg0 += (float)__popcll(mt[u][r0]);
    dg1 += (float)__popcll(mt[u][r1]);
  }
  deg_s[r0] = dg0; deg_s[r1] = dg1;
  __syncthreads();
  // d2 = A . deg
  float d20 = 0.f, d21 = 0.f;
  #pragma unroll
  for (int u = 0; u < 8; u++){
    u64 m0 = mt[u][r0];
    while (m0){ int l = __builtin_ctzll(m0); m0 &= m0 - 1; d20 += deg_s[u * 64 + l]; }
    u64 m1 = mt[u][r1];
    while (m1){ int l = __builtin_ctzll(m1); m1 &= m1 - 1; d21 += deg_s[u * 64 + l]; }
  }
  d2_s[r0] = d20; d2_s[r1] = d21;
  __syncthreads();
  // d3 = A . d2 ; dd = rsqrt(max(rowsum(M),1))
  float d30 = 0.f, d31 = 0.f;
  #pragma unroll
  for (int u = 0; u < 8; u++){
    u64 m0 = mt[u][r0];
    while (m0){ int l = __builtin_ctzll(m0); m0 &= m0 - 1; d30 += d2_s[u * 64 + l]; }
    u64 m1 = mt[u][r1];
    while (m1){ int l = __builtin_ctzll(m1); m1 &= m1 - 1; d31 += d2_s[u * 64 + l]; }
  }
  const float dd0 = rsqrtf(fmaxf(c0 + c1 * dg0 + c2 * d20 + c3 * d30, 1.0f));
  const float dd1 = rsqrtf(fmaxf(c0 + c1 * dg1 + c2 * d21 + c3 * d31, 1.0f));
  __syncthreads();                     // deg_s/d2_s dead; zA may now be written
  // z = [dd, dd*x]
  {
    const float* xr0 = x + ((size_t)g * NDIM + r0) * FIN;
    const float* xr1 = x + ((size_t)g * NDIM + r1) * FIN;
    zA[r0 * 8] = dd0; zA[r1 * 8] = dd1;
    #pragma unroll
    for (int f = 0; f < FIN; f++){
      zA[r0 * 8 + 1 + f] = dd0 * xr0[f];
      zA[r1 * 8 + 1 + f] = dd1 * xr1[f];
    }
    if (own0) dvec[g * NDIM + r0] = dd0;
    if (own1) dvec[g * NDIM + r1] = dd1;
  }
  __syncthreads();
  float aw1[8], aw2[8], aw3[8];
  // w1 = A . z  (zB <- walk zA)
  {
    float a0[8] = {0,0,0,0,0,0,0,0}, a1[8] = {0,0,0,0,0,0,0,0};
    #pragma unroll
    for (int u = 0; u < 8; u++){
      u64 m0 = mt[u][r0];
      while (m0){
        int l = __builtin_ctzll(m0); m0 &= m0 - 1;
        const float4* p = (const float4*)(zA + (u * 64 + l) * 8);
        float4 v0 = p[0], v1 = p[1];
        a0[0]+=v0.x; a0[1]+=v0.y; a0[2]+=v0.z; a0[3]+=v0.w;
        a0[4]+=v1.x; a0[5]+=v1.y; a0[6]+=v1.z; a0[7]+=v1.w;
      }
      u64 m1 = mt[u][r1];
      while (m1){
        int l = __builtin_ctzll(m1); m1 &= m1 - 1;
        const float4* p = (const float4*)(zA + (u * 64 + l) * 8);
        float4 v0 = p[0], v1 = p[1];
        a1[0]+=v0.x; a1[1]+=v0.y; a1[2]+=v0.z; a1[3]+=v0.w;
        a1[4]+=v1.x; a1[5]+=v1.y; a1[6]+=v1.z; a1[7]+=v1.w;
      }
    }
    #pragma unroll
    for (int e = 0; e < 8; e++){ zB[r0 * 8 + e] = a0[e]; zB[r1 * 8 + e] = a1[e]; }
    #pragma unroll
    for (int e = 0; e < 8; e++) aw1[e] = own0 ? a0[e] : a1[e];
  }
  __syncthreads();
  // w2 = A . w1  (zA <- walk zB)
  {
    float a0[8] = {0,0,0,0,0,0,0,0}, a1[8] = {0,0,0,0,0,0,0,0};
    #pragma unroll
    for (int u = 0; u < 8; u++){
      u64 m0 = mt[u][r0];
      while (m0){
        int l = __builtin_ctzll(m0); m0 &= m0 - 1;
        const float4* p = (const float4*)(zB + (u * 64 + l) * 8);
        float4 v0 = p[0], v1 = p[1];
        a0[0]+=v0.x; a0[1]+=v0.y; a0[2]+=v0.z; a0[3]+=v0.w;
        a0[4]+=v1.x; a0[5]+=v1.y; a0[6]+=v1.z; a0[7]+=v1.w;
      }
      u64 m1 = mt[u][r1];
      while (m1){
        int l = __builtin_ctzll(m1); m1 &= m1 - 1;
        const float4* p = (const float4*)(zB + (u * 64 + l) * 8);
        float4 v0 = p[0], v1 = p[1];
        a1[0]+=v0.x; a1[1]+=v0.y; a1[2]+=v0.z; a1[3]+=v0.w;
        a1[4]+=v1.x; a1[5]+=v1.y; a1[6]+=v1.z; a1[7]+=v1.w;
      }
    }
    __syncthreads();                   // all zB reads done before zA overwrite
    #pragma unroll
    for (int e = 0; e < 8; e++){ zA[r0 * 8 + e] = a0[e]; zA[r1 * 8 + e] = a1[e]; }
    #pragma unroll
    for (int e = 0; e < 8; e++) aw2[e] = own0 ? a0[e] : a1[e];
  }
  // stage weights into freed zB region — STRIDED (256 threads, 448 elems!)
  for (int q = tid; q < FIN * HID; q += 256) Wl[q] = w1[q];
  if (tid < HID){ Wl[448 + tid] = pvec[tid]; Wl[512 + tid] = b1[tid]; }
  __syncthreads();
  // w3 for OWN rows only + finalize
  if (own0 | own1){
    const int ro = own0 ? r0 : r1;
    const float dd = own0 ? dd0 : dd1;
    const int row = g * NDIM + ro;
    #pragma unroll
    for (int e = 0; e < 8; e++) aw3[e] = 0.f;
    #pragma unroll
    for (int u = 0; u < 8; u++){
      u64 mm = mt[u][ro];
      while (mm){
        int l = __builtin_ctzll(mm); mm &= mm - 1;
        const float4* p = (const float4*)(zA + (u * 64 + l) * 8);
        float4 v0 = p[0], v1 = p[1];
        aw3[0]+=v0.x; aw3[1]+=v0.y; aw3[2]+=v0.z; aw3[3]+=v0.w;
        aw3[4]+=v1.x; aw3[5]+=v1.y; aw3[6]+=v1.z; aw3[7]+=v1.w;
      }
    }
    const float s2v = dd * (c0 * dd + c1 * aw1[0] + c2 * aw2[0] + c3 * aw3[0]);
    float yin[FIN];
    #pragma unroll
    for (int f = 0; f < FIN; f++){
      float zv = dd * x[(size_t)row * FIN + f];
      float y = c0 * zv;
      y += c1 * aw1[f + 1];
      y += c2 * aw2[f + 1];
      y += c3 * aw3[f + 1];
      yin[f] = dd * y;
    }
    float hv[HID];
    float s1 = 0.f;
    #pragma unroll
    for (int o = 0; o < HID; o++){
      float zz = Wl[512 + o];
      #pragma unroll
      for (int f = 0; f < FIN; f++) zz = fmaf(yin[f], Wl[f * HID + o], zz);
      hv[o] = fmaxf(zz, 0.f);
      s1 = fmaf(hv[o], Wl[448 + o], s1);
    }
    score[row] = tanhf(beta[0] * s1 + beta[1] * s2v);
    float* hr = hbuf + (size_t)row * HID;
    #pragma unroll
    for (int o = 0; o < HID; o++) hr[o] = hv[o];
  }
}

// ---- top-k rank selection + xp gather -------------------------------------
__global__ __launch_bounds__(512) void topk_kernel(const float* __restrict__ score,
                                                   const float* __restrict__ hbuf,
                                                   int* __restrict__ idxOut,
                                                   float* __restrict__ xp)
{
  const int g = blockIdx.x, t = threadIdx.x;        // 512
  __shared__ float sv[NDIM];
  sv[t] = score[g * NDIM + t];
  __syncthreads();
  const float v = sv[t];
  int rank = 0;
  #pragma unroll 8
  for (int j = 0; j < NDIM; j++){
    float u_ = sv[j];
    rank += (u_ > v || (u_ == v && j < t)) ? 1 : 0;
  }
  if (rank < KPOOL){
    idxOut[g * KPOOL + rank] = t;
    const float* hr = hbuf + ((size_t)g * NDIM + t) * HID;
    float* xr = xp + ((size_t)g * KPOOL + rank) * HID;
    #pragma unroll
    for (int o = 0; o < HID; o++) xr[o] = hr[o] * v;
  }
}

// ---- pooled adjacency (fused A2p): Apool = Mn[idx,idx] + I, di ------------
__global__ __launch_bounds__(512) void pool_kernel(
    const u64* __restrict__ maskT, const int* __restrict__ idx,
    const float* __restrict__ dvec, const float* __restrict__ panw,
    float* __restrict__ Apool, float* __restrict__ di)
{
  const int b = blockIdx.x;
  const int g = b >> 3, rowgrp = b & 7;
  const int tid = threadIdx.x, w = tid >> 6, lane = tid & 63;
  __shared__ u64 mt[8][NDIM];                    // 32 KB
  __shared__ unsigned char arow[16][NDIM];       // 8 KB
  __shared__ int idxs[KPOOL];
  __shared__ float dp[KPOOL];
  {
    const uint4* s4 = (const uint4*)(maskT + (size_t)g * 8 * NDIM);
    uint4* d4 = (uint4*)&mt[0][0];
    #pragma unroll
    for (int s = 0; s < 4; s++) d4[tid + 512 * s] = s4[tid + 512 * s];
  }
  if (tid < KPOOL){
    int ia = idx[g * KPOOL + tid];
    idxs[tid] = ia;
    dp[tid] = dvec[g * NDIM + ia];
  }
  __syncthreads();
  // compute the 16 pooled A2 rows in-block (register-tiled popcounts)
  #pragma unroll
  for (int e = 0; e < 2; e++){
    const int j = w * 2 + e;
    const int ir = idxs[rowgrp * 16 + j];
    u64 rm[8];
    #pragma unroll
    for (int u = 0; u < 8; u++) rm[u] = mt[u][ir];   // wave-uniform broadcast
    #pragma unroll
    for (int q = 0; q < 8; q++){
      int c = 0;
      #pragma unroll
      for (int u = 0; u < 8; u++)
        c += (int)__popcll(mt[u][q * 64 + lane] & rm[u]);
      arow[j][q * 64 + lane] = (unsigned char)c;
    }
  }
  const int c0i = lane * 2, c1i = lane * 2 + 1;
  const int ic0 = idxs[c0i], ic1 = idxs[c1i];
  u64 cm0[8], cm1[8];
  #pragma unroll
  for (int u = 0; u < 8; u++){
    cm0[u] = mt[u][ic0];
    cm1[u] = mt[u][ic1];
  }
  __syncthreads();
  const float w0 = panw[0], ww1 = panw[1], ww2 = panw[2], ww3 = panw[3];
  const float cc0 = w0, cc1 = cc0 * ww1, cc2 = cc1 * ww2, cc3 = cc2 * ww3;
  const float dc0 = dp[c0i], dc1 = dp[c1i];
  #pragma unroll
  for (int e = 0; e < 2; e++){
    const int j = w * 2 + e;
    const int r = rowgrp * 16 + j;
    const int ir = idxs[r];
    const float dpr = dp[r];
    const unsigned char* aj = arow[j];
    float a30 = 0.f, a31 = 0.f;
    #pragma unroll
    for (int u = 0; u < 8; u++){
      u64 m0 = cm0[u];
      while (m0){ int l = __builtin_ctzll(m0); m0 &= m0 - 1; a30 += (float)aj[u * 64 + l]; }
      u64 m1 = cm1[u];
      while (m1){ int l = __builtin_ctzll(m1); m1 &= m1 - 1; a31 += (float)aj[u * 64 + l]; }
    }
    float ab0 = (float)((cm0[ir >> 6] >> (ir & 63)) & 1ull);
    float ab1 = (float)((cm1[ir >> 6] >> (ir & 63)) & 1ull);
    float m0 = fmaf(cc3, a30, fmaf(cc2, (float)aj[ic0], cc1 * ab0));
    float m1 = fmaf(cc3, a31, fmaf(cc2, (float)aj[ic1], cc1 * ab1));
    if (r == c0i) m0 += cc0;
    if (r == c1i) m1 += cc0;
    float v0 = m0 * dpr * dc0;
    float v1 = m1 * dpr * dc1;
    if (r == c0i) v0 += 1.0f;
    if (r == c1i) v1 += 1.0f;
    float2 vv = make_float2(v0, v1);
    *(float2*)&Apool[((size_t)g * KPOOL + r) * KPOOL + c0i] = vv;
    float s = wred64(v0 + v1);
    if (lane == 0) di[g * KPOOL + r] = s > 0.f ? rsqrtf(s) : 0.f;
  }
}

// ---------------- pooled GCN: h2 = relu((An xp) W + b) ---------------------
__global__ __launch_bounds__(256) void gcn_kernel(
    const float* __restrict__ Apool, const float* __restrict__ di,
    const float* __restrict__ xp, const float* __restrict__ gw,
    const float* __restrict__ gb, float* __restrict__ h2)
{
  const int wid = threadIdx.x >> 6, lane = threadIdx.x & 63;
  const int row = blockIdx.x * 4 + wid;
  const int g = row >> 7, r = row & 127;
  const float dir = di[g * KPOOL + r];
  float acc = 0.f;
  for (int b = 0; b < KPOOL; b++){
    float an = Apool[(size_t)row * KPOOL + b] * dir * di[g * KPOOL + b];
    acc = fmaf(an, xp[((size_t)g * KPOOL + b) * HID + lane], acc);
  }
  __shared__ float ts[4][HID];
  ts[wid][lane] = acc;
  __syncthreads();
  float z = gb[lane];
  for (int f = 0; f < HID; f++) z = fmaf(ts[wid][f], gw[f * HID + lane], z);
  h2[(size_t)row * HID + lane] = fmaxf(z, 0.f);
}

// ---------------- head: pooled sum + linear + log_softmax ------------------
__global__ void head_kernel(const float* __restrict__ h2,
                            const float* __restrict__ lw,
                            const float* __restrict__ lb,
                            float* __restrict__ out)
{
  const int g = blockIdx.x;
  const int lane = threadIdx.x;
  float p = 0.f;
  for (int k = 0; k < KPOOL; k++) p += h2[((size_t)g * KPOOL + k) * HID + lane];
  float z0 = p * lw[lane * CLS + 0];
  float z1 = p * lw[lane * CLS + 1];
  z0 = wred64(z0);
  z1 = wred64(z1);
  if (lane == 0){
    float l0 = z0 + lb[0], l1 = z1 + lb[1];
    float m = fmaxf(l0, l1);
    float lse = m + logf(expf(l0 - m) + expf(l1 - m));
    out[g * CLS + 0] = l0 - lse;
    out[g * CLS + 1] = l1 - lse;
  }
}

extern "C" void kernel_launch(void* const* d_in, const int* in_sizes, int n_in,
                              void* d_out, int out_size, void* d_ws, size_t ws_size,
                              hipStream_t stream)
{
  const float* x    = (const float*)d_in[0];
  const float* adj  = (const float*)d_in[1];
  const float* panw = (const float*)d_in[2];
  const float* w1   = (const float*)d_in[3];
  const float* b1   = (const float*)d_in[4];
  const float* pvec = (const float*)d_in[5];
  const float* beta = (const float*)d_in[6];
  const float* gw   = (const float*)d_in[7];
  const float* gbv  = (const float*)d_in[8];
  const float* lw   = (const float*)d_in[9];
  const float* lb   = (const float*)d_in[10];
  float* out = (float*)d_out;

  char* ws = (char*)d_ws;
  const size_t NR = (size_t)G * NDIM;            // 32768 rows
  u64* maskT = (u64*)ws;                         // 2 MB
  char* p = ws + (1 << 21);
  float* dvec  = (float*)p;  p += NR * 4;
  float* score = (float*)p;  p += NR * 4;
  float* hbuf  = (float*)p;  p += NR * HID * 4;  // 8 MB
  int*   idx   = (int*)p;    p += (size_t)G * KPOOL * 4;
  float* xp    = (float*)p;  p += (size_t)G * KPOOL * HID * 4;
  float* Apool = (float*)p;  p += (size_t)G * KPOOL * KPOOL * 4;
  float* di    = (float*)p;  p += (size_t)G * KPOOL * 4;
  float* h2    = (float*)p;

  mask_kernel<<<G * NDIM / 4, 256, 0, stream>>>(adj, maskT);
  mega_kernel<<<512, 256, 0, stream>>>(maskT, x, panw, w1, b1, pvec, beta,
                                       dvec, score, hbuf);
  topk_kernel<<<G, 512, 0, stream>>>(score, hbuf, idx, xp);
  pool_kernel<<<G * 8, 512, 0, stream>>>(maskT, idx, dvec, panw, Apool, di);
  gcn_kernel<<<G * KPOOL / 4, 256, 0, stream>>>(Apool, di, xp, gw, gbv, h2);
  head_kernel<<<G, 64, 0, stream>>>(h2, lw, lb, out);
}